// Round 3
// baseline (2166.203 us; speedup 1.0000x reference)
//
#include <hip/hip_runtime.h>

// LIF two-layer SNN, bit-exact emulation of the f32 OpenBLAS-style reference
// (kc=320 K-blocking, sequential ascending-k f32 chains per block, block
// partials combined in order; LIF = separate f32 mul then add).
// Round 7: G=2 batch-pair union gathers. 256 blocks x 512 threads; each block
// processes 2 batch elements, iterating the ASCENDING UNION of their active
// rows; each row loaded once (dwordx2 per thread, 2 cols) and accumulated
// into both chains via s = fma(mask, w, s) with mask in {1.0, 0.0}.
// fma(1,w,s) == fadd(s,w) bitwise; fma(0,w,s) adds +-0.0 which is exact
// (partials are never -0.0). kc boundaries are k-values -> identical chain
// splits. ~6.6% fewer L2 bytes at the measured 34.5 TB/s ceiling.

#define T_STEPS 128
#define BATCH   512
#define NLAB    512
#define HID     1024
#define SEM     1024

// 32x32 tiled transpose, block = (32,8). R,C multiples of 32. Exact copies.
__global__ __launch_bounds__(256) void transpose32(const float* __restrict__ in,
                                                   float* __restrict__ out,
                                                   int R, int C) {
    __shared__ float tile[32][33];
    const int c0 = blockIdx.x * 32, r0 = blockIdx.y * 32;
    const int x = threadIdx.x, y0 = threadIdx.y;
#pragma unroll
    for (int i = 0; i < 32; i += 8)
        tile[y0 + i][x] = in[(size_t)(r0 + y0 + i) * C + (c0 + x)];
    __syncthreads();
#pragma unroll
    for (int i = 0; i < 32; i += 8)
        out[(size_t)(c0 + y0 + i) * R + (r0 + x)] = tile[x][y0 + i];
}

// Union gather: sequential ascending-k chains over list[lo..hi) of packed
// entries (row | mb0<<16 | mb1<<17), row stride 1024 floats. Each thread
// owns 2 columns (dwordx2) and 2 batch chains -> 4 partial sums.
// s = fma(mask, w, s): mask=1.0 -> bitwise fadd; mask=0.0 -> exact no-op.
// Per-(b,col) fadd order is strictly k-ascending over b's actives -> bit-exact.
__device__ __forceinline__ void gather22(const int* __restrict__ list,
                                         int lo, int hi,
                                         const float* __restrict__ base, // w + 2*tid
                                         float s[4]) {
    float s0 = 0.0f, s1 = 0.0f, s2 = 0.0f, s3 = 0.0f;
    int k = lo;
    for (; k + 16 <= hi; k += 16) {
        float2 wv[16];
        int    e[16];
#pragma unroll
        for (int j = 0; j < 16; ++j) {
            e[j] = __builtin_amdgcn_readfirstlane(list[k + j]);
            wv[j] = *reinterpret_cast<const float2*>(base + ((size_t)(e[j] & 0xFFFF) << 10));
        }
#pragma unroll
        for (int j = 0; j < 16; ++j) {
            const float f0 = (e[j] & 0x10000) ? 1.0f : 0.0f;
            const float f1 = (e[j] & 0x20000) ? 1.0f : 0.0f;
            s0 = __fmaf_rn(f0, wv[j].x, s0);
            s1 = __fmaf_rn(f0, wv[j].y, s1);
            s2 = __fmaf_rn(f1, wv[j].x, s2);
            s3 = __fmaf_rn(f1, wv[j].y, s3);
        }
    }
    for (; k + 8 <= hi; k += 8) {
        float2 wv[8];
        int    e[8];
#pragma unroll
        for (int j = 0; j < 8; ++j) {
            e[j] = __builtin_amdgcn_readfirstlane(list[k + j]);
            wv[j] = *reinterpret_cast<const float2*>(base + ((size_t)(e[j] & 0xFFFF) << 10));
        }
#pragma unroll
        for (int j = 0; j < 8; ++j) {
            const float f0 = (e[j] & 0x10000) ? 1.0f : 0.0f;
            const float f1 = (e[j] & 0x20000) ? 1.0f : 0.0f;
            s0 = __fmaf_rn(f0, wv[j].x, s0);
            s1 = __fmaf_rn(f0, wv[j].y, s1);
            s2 = __fmaf_rn(f1, wv[j].x, s2);
            s3 = __fmaf_rn(f1, wv[j].y, s3);
        }
    }
    for (; k < hi; ++k) {
        const int e = __builtin_amdgcn_readfirstlane(list[k]);
        const float2 wv = *reinterpret_cast<const float2*>(base + ((size_t)(e & 0xFFFF) << 10));
        const float f0 = (e & 0x10000) ? 1.0f : 0.0f;
        const float f1 = (e & 0x20000) ? 1.0f : 0.0f;
        s0 = __fmaf_rn(f0, wv.x, s0);
        s1 = __fmaf_rn(f0, wv.y, s1);
        s2 = __fmaf_rn(f1, wv.x, s2);
        s3 = __fmaf_rn(f1, wv.y, s3);
    }
    s[0] = s0; s[1] = s1; s[2] = s2; s[3] = s3;
}

__global__ __launch_bounds__(512)
void snn_kernel(const float* __restrict__ spikes,   // (T, B, NLAB)
                const float* __restrict__ w1t,      // (NLAB, HID) = W1^T
                const float* __restrict__ w2t,      // (HID, SEM)  = W2^T
                float* __restrict__ out) {          // (B*HID) ++ (B*SEM)
    __shared__ int wc1[8];            // per-wave union counts, input spikes
    __shared__ int wc2[8];            // per-wave union counts, layer-1 spikes
    __shared__ int wc2pA;             // partial: union h-entries with tid in [128,160)
    __shared__ int wc2pC;             // partial: union h-entries with tid in [448,480)
    __shared__ __align__(16) int list1[NLAB];   // ascending union, packed masks
    __shared__ __align__(16) int list2[HID];

    const int tid  = threadIdx.x;               // 0..511
    const int w    = tid >> 6;                  // wave 0..7
    const int lane = tid & 63;
    const unsigned long long below = (1ull << lane) - 1ull;

    const int b0 = 2 * blockIdx.x;              // batch pair

    // per-thread state: [b][col], cols = 2*tid, 2*tid+1
    float v1[4] = {0.0f, 0.0f, 0.0f, 0.0f};
    float v2[4] = {0.0f, 0.0f, 0.0f, 0.0f};
    int   c1[4] = {0, 0, 0, 0};
    int   c2[4] = {0, 0, 0, 0};

    const float* sp0 = spikes + (size_t)b0 * NLAB + tid;         // b0, k=tid
    const float* sp1 = sp0 + NLAB;                               // b1, k=tid
    const float* w1b = w1t + 2 * tid;
    const float* w2b = w2t + 2 * tid;

    // prefetch spikes for t=0
    float sv0 = *sp0;
    float sv1 = *sp1;

    for (int t = 0; t < T_STEPS; ++t) {
        // ---- stage 1a: union ballot over input spikes (k = tid) ----
        const bool a0 = (sv0 != 0.0f);
        const bool a1 = (sv1 != 0.0f);
        const bool u  = a0 | a1;
        const unsigned long long mu = __ballot(u);
        if (lane == 0) wc1[w] = __popcll(mu);
        const int pre1 = __popcll(mu & below);
        __syncthreads();                        // wc1 ready; prev stage-3 done

        // ---- stage 1b: deterministic ascending compaction ----
        if (u) {
            int base = 0;
            for (int i = 0; i < w; ++i) base += wc1[i];
            list1[base + pre1] = tid | (a0 ? 0x10000 : 0) | (a1 ? 0x20000 : 0);
        }
        __syncthreads();                        // list1 ready

        // prefetch spikes for t+1; overlaps gather compute
        if (t + 1 < T_STEPS) {
            sv0 = sp0[(size_t)(t + 1) * (BATCH * NLAB)];
            sv1 = sp1[(size_t)(t + 1) * (BATCH * NLAB)];
        }

        // ---- stage 2: layer 1, cols h = 2*tid+c. kc split at k=320 (= wave 5) ----
        bool s00, s01, s10, s11;                // spk[b][col]
        int  preh;
        {
            int nA = 0, n1 = 0;
            {
                int s = 0;
#pragma unroll
                for (int i = 0; i < 8; ++i) { s += wc1[i]; if (i == 4) nA = s; }
                n1 = s;
            }
            float xA[4], xB[4];
            gather22(list1, 0,  nA, w1b, xA);
            gather22(list1, nA, n1, w1b, xB);
#pragma unroll
            for (int j = 0; j < 4; ++j) {
                const float x1 = __fadd_rn(xA[j], xB[j]);
                v1[j] = __fadd_rn(__fmul_rn(0.95f, v1[j]), x1);
            }
            s00 = (v1[0] > 1.0f); if (s00) { c1[0]++; v1[0] = 0.0f; }
            s01 = (v1[1] > 1.0f); if (s01) { c1[1]++; v1[1] = 0.0f; }
            s10 = (v1[2] > 1.0f); if (s10) { c1[2]++; v1[2] = 0.0f; }
            s11 = (v1[3] > 1.0f); if (s11) { c1[3]++; v1[3] = 0.0f; }

            // union per hidden h: h=2*tid (col0), h=2*tid+1 (col1)
            const bool u0 = s00 | s10;
            const bool u1 = s01 | s11;
            const unsigned long long m0 = __ballot(u0);
            const unsigned long long m1 = __ballot(u1);
            if (lane == 0) {
                wc2[w] = __popcll(m0) + __popcll(m1);
                // h<320 <=> tid<160 : wave 2, lane<32 partial
                if (w == 2)
                    wc2pA = __popcll(m0 & 0xFFFFFFFFull) + __popcll(m1 & 0xFFFFFFFFull);
                // h<960 <=> tid<480 : wave 7, lane<32 partial
                if (w == 7)
                    wc2pC = __popcll(m0 & 0xFFFFFFFFull) + __popcll(m1 & 0xFFFFFFFFull);
            }
            preh = __popcll(m0 & below) + __popcll(m1 & below);

            __syncthreads();                    // wc2 ready

            int base = 0;
            for (int i = 0; i < w; ++i) base += wc2[i];
            int p = base + preh;                // own entries consecutive, h asc
            if (u0) list2[p++] = (2 * tid)     | (s00 ? 0x10000 : 0) | (s10 ? 0x20000 : 0);
            if (u1) list2[p]   = (2 * tid + 1) | (s01 ? 0x10000 : 0) | (s11 ? 0x20000 : 0);
        }
        __syncthreads();                        // list2 ready

        // ---- stage 3: layer 2. kc blocks at h = 320 / 640 / 960 ----
        {
            int nA, nB = 0, nC, n2 = 0;
            {
                int s = 0;
#pragma unroll
                for (int i = 0; i < 8; ++i) { s += wc2[i]; if (i == 4) nB = s; }
                n2 = s;
            }
            nA = wc2[0] + wc2[1] + wc2pA;                                   // h < 320
            nC = wc2[0] + wc2[1] + wc2[2] + wc2[3] + wc2[4] + wc2[5] + wc2[6] + wc2pC; // h < 960
            float t1[4], t2[4], t3[4], t4[4];
            gather22(list2, 0,  nA, w2b, t1);
            gather22(list2, nA, nB, w2b, t2);
            gather22(list2, nB, nC, w2b, t3);
            gather22(list2, nC, n2, w2b, t4);
#pragma unroll
            for (int j = 0; j < 4; ++j) {
                const float x2 = __fadd_rn(__fadd_rn(__fadd_rn(t1[j], t2[j]), t3[j]), t4[j]);
                v2[j] = __fadd_rn(__fmul_rn(0.95f, v2[j]), x2);
                if (v2[j] > 1.0f) { c2[j]++; v2[j] = 0.0f; }
            }
        }
        __syncthreads();                        // lists/counts free for next iter
    }

    const float sc = 1.0f / 128.0f;
    // layer-1 means: out[b*HID + h], cols 2*tid, 2*tid+1 contiguous
    {
        const float2 o0 = make_float2((float)c1[0] * sc, (float)c1[1] * sc);
        const float2 o1 = make_float2((float)c1[2] * sc, (float)c1[3] * sc);
        *reinterpret_cast<float2*>(out + (size_t)b0 * HID + 2 * tid)       = o0;
        *reinterpret_cast<float2*>(out + (size_t)(b0 + 1) * HID + 2 * tid) = o1;
    }
    // layer-2 means
    {
        float* o2b = out + (size_t)BATCH * HID;
        const float2 o0 = make_float2((float)c2[0] * sc, (float)c2[1] * sc);
        const float2 o1 = make_float2((float)c2[2] * sc, (float)c2[3] * sc);
        *reinterpret_cast<float2*>(o2b + (size_t)b0 * SEM + 2 * tid)       = o0;
        *reinterpret_cast<float2*>(o2b + (size_t)(b0 + 1) * SEM + 2 * tid) = o1;
    }
}

extern "C" void kernel_launch(void* const* d_in, const int* in_sizes, int n_in,
                              void* d_out, int out_size, void* d_ws, size_t ws_size,
                              hipStream_t stream) {
    const float* spikes = (const float*)d_in[0];  // (128, 512, 512)
    const float* W1     = (const float*)d_in[1];  // (1024, 512)
    const float* W2     = (const float*)d_in[2];  // (1024, 1024)
    float* out = (float*)d_out;

    float* w1t = (float*)d_ws;                    // (512, 1024)
    float* w2t = w1t + (size_t)NLAB * HID;        // (1024, 1024) — 6 MB total

    dim3 tb(32, 8);
    transpose32<<<dim3(NLAB / 32, HID / 32), tb, 0, stream>>>(W1, w1t, HID, NLAB);
    transpose32<<<dim3(HID / 32, SEM / 32),  tb, 0, stream>>>(W2, w2t, SEM, HID);

    snn_kernel<<<BATCH / 2, 512, 0, stream>>>(spikes, w1t, w2t, out);
}

// Round 4
// 1886.053 us; speedup vs baseline: 1.1485x; 1.1485x over previous
//
#include <hip/hip_runtime.h>

// LIF two-layer SNN, bit-exact emulation of the f32 OpenBLAS-style reference
// (kc=320 K-blocking, sequential ascending-k f32 chains per block, block
// partials combined in order; LIF = separate f32 mul then add).
// Round 8: G=2 batch-pair union AT ROUND-6 GEOMETRY. 256 blocks x 256
// threads; thread owns 4 consecutive cols (dwordx4 per row, 1KB/wave-instr,
// unchanged vs r6). Block iterates the ascending UNION of its two batch
// elements' active rows; application = 4 v_pk_fma_f32 per row per wave
// (__builtin_elementwise_fma on float2, wave-uniform {1,0} mask) == same
// VALU instruction count as r6's 4 fadds, rows -6.6%.
// Bit-exact: pk_fma(1,w,s) == fadd(s,w) bitwise; pk_fma(0,w,s) adds +-0.0
// which is exact (accumulators are never -0.0). kc splits are k-values ->
// identical chain structure. r7 lesson: never widen the per-row wave-instr
// budget (dwordx2 + redundant fma doubled vmem+VALU -> +45%).

#define T_STEPS 128
#define BATCH   512
#define NLAB    512
#define HID     1024
#define SEM     1024

typedef float f32x2 __attribute__((ext_vector_type(2)));

// 32x32 tiled transpose, block = (32,8). R,C multiples of 32. Exact copies.
__global__ __launch_bounds__(256) void transpose32(const float* __restrict__ in,
                                                   float* __restrict__ out,
                                                   int R, int C) {
    __shared__ float tile[32][33];
    const int c0 = blockIdx.x * 32, r0 = blockIdx.y * 32;
    const int x = threadIdx.x, y0 = threadIdx.y;
#pragma unroll
    for (int i = 0; i < 32; i += 8)
        tile[y0 + i][x] = in[(size_t)(r0 + y0 + i) * C + (c0 + x)];
    __syncthreads();
#pragma unroll
    for (int i = 0; i < 32; i += 8)
        out[(size_t)(c0 + y0 + i) * R + (r0 + x)] = tile[x][y0 + i];
}

// Union gather: sequential ascending-k chains over list[lo..hi) of packed
// entries (row | mb0<<16 | mb1<<17), row stride 1024 floats. Thread owns 4
// consecutive cols (dwordx4) for BOTH batch elements: 4 pk_fma per row.
// s[] = {b0 cols01, b0 cols23, b1 cols01, b1 cols23}.
// Per-(b,col) fadd order is strictly k-ascending over b's actives -> bit-exact.
__device__ __forceinline__ void gatherU(const int* __restrict__ list,
                                        int lo, int hi,
                                        const float* __restrict__ base, // w + 4*tid
                                        f32x2 s[4]) {
    f32x2 s00 = {0.0f, 0.0f}, s01 = {0.0f, 0.0f};
    f32x2 s10 = {0.0f, 0.0f}, s11 = {0.0f, 0.0f};
    int k = lo;
    for (; k + 16 <= hi; k += 16) {
        int    e[16];
        float4 wv[16];
#pragma unroll
        for (int j = 0; j < 16; ++j) {
            e[j] = __builtin_amdgcn_readfirstlane(list[k + j]);
            wv[j] = *reinterpret_cast<const float4*>(base + ((size_t)(e[j] & 0xFFFF) << 10));
        }
#pragma unroll
        for (int j = 0; j < 16; ++j) {
            const float f0 = (e[j] & 0x10000) ? 1.0f : 0.0f;
            const float f1 = (e[j] & 0x20000) ? 1.0f : 0.0f;
            const f32x2 m0 = {f0, f0}, m1 = {f1, f1};
            const f32x2 w01 = {wv[j].x, wv[j].y}, w23 = {wv[j].z, wv[j].w};
            s00 = __builtin_elementwise_fma(m0, w01, s00);
            s01 = __builtin_elementwise_fma(m0, w23, s01);
            s10 = __builtin_elementwise_fma(m1, w01, s10);
            s11 = __builtin_elementwise_fma(m1, w23, s11);
        }
    }
    for (; k + 8 <= hi; k += 8) {
        int    e[8];
        float4 wv[8];
#pragma unroll
        for (int j = 0; j < 8; ++j) {
            e[j] = __builtin_amdgcn_readfirstlane(list[k + j]);
            wv[j] = *reinterpret_cast<const float4*>(base + ((size_t)(e[j] & 0xFFFF) << 10));
        }
#pragma unroll
        for (int j = 0; j < 8; ++j) {
            const float f0 = (e[j] & 0x10000) ? 1.0f : 0.0f;
            const float f1 = (e[j] & 0x20000) ? 1.0f : 0.0f;
            const f32x2 m0 = {f0, f0}, m1 = {f1, f1};
            const f32x2 w01 = {wv[j].x, wv[j].y}, w23 = {wv[j].z, wv[j].w};
            s00 = __builtin_elementwise_fma(m0, w01, s00);
            s01 = __builtin_elementwise_fma(m0, w23, s01);
            s10 = __builtin_elementwise_fma(m1, w01, s10);
            s11 = __builtin_elementwise_fma(m1, w23, s11);
        }
    }
    for (; k < hi; ++k) {
        const int e = __builtin_amdgcn_readfirstlane(list[k]);
        const float4 wv = *reinterpret_cast<const float4*>(base + ((size_t)(e & 0xFFFF) << 10));
        const float f0 = (e & 0x10000) ? 1.0f : 0.0f;
        const float f1 = (e & 0x20000) ? 1.0f : 0.0f;
        const f32x2 m0 = {f0, f0}, m1 = {f1, f1};
        const f32x2 w01 = {wv.x, wv.y}, w23 = {wv.z, wv.w};
        s00 = __builtin_elementwise_fma(m0, w01, s00);
        s01 = __builtin_elementwise_fma(m0, w23, s01);
        s10 = __builtin_elementwise_fma(m1, w01, s10);
        s11 = __builtin_elementwise_fma(m1, w23, s11);
    }
    s[0] = s00; s[1] = s01; s[2] = s10; s[3] = s11;
}

__global__ __launch_bounds__(256)
void snn_kernel(const float* __restrict__ spikes,   // (T, B, NLAB)
                const float* __restrict__ w1t,      // (NLAB, HID) = W1^T
                const float* __restrict__ w2t,      // (HID, SEM)  = W2^T
                float* __restrict__ out) {          // (B*HID) ++ (B*SEM)
    __shared__ int wc1[4];            // per-wave union counts, input spikes
    __shared__ int wc1p;              // partial: union k in [256,320) (wave 2, l<32)
    __shared__ int wc2[4];            // per-wave union counts, layer-1 spikes
    __shared__ int wc2p[3];           // partials at h=320 (w1,l<16), 640 (w2,l<32), 960 (w3,l<48)
    __shared__ __align__(16) int list1[NLAB];   // ascending union, packed masks
    __shared__ __align__(16) int list2[HID];

    const int tid  = threadIdx.x;               // 0..255
    const int w    = tid >> 6;                  // wave 0..3
    const int lane = tid & 63;
    const unsigned long long below = (1ull << lane) - 1ull;

    const int b0 = 2 * blockIdx.x;              // batch pair

    // state: v[2 pairs per b][b] ; index: 0=b0 cols01, 1=b0 cols23, 2=b1 cols01, 3=b1 cols23
    f32x2 v1[4] = {{0,0},{0,0},{0,0},{0,0}};
    f32x2 v2[4] = {{0,0},{0,0},{0,0},{0,0}};
    int   c1[8] = {0,0,0,0,0,0,0,0};            // [b*4 + col]
    int   c2[8] = {0,0,0,0,0,0,0,0};

    // thread covers inputs k = 2*tid, 2*tid+1 (both b's) and cols 4*tid..4*tid+3
    const float* sp0 = spikes + (size_t)b0 * NLAB + 2 * tid;
    const float* sp1 = sp0 + NLAB;
    const float* w1b = w1t + 4 * tid;
    const float* w2b = w2t + 4 * tid;

    // prefetch spikes for t=0
    float2 sv0 = *reinterpret_cast<const float2*>(sp0);
    float2 sv1 = *reinterpret_cast<const float2*>(sp1);

    for (int t = 0; t < T_STEPS; ++t) {
        // ---- stage 1a: union ballots over input spikes (k = 2*tid+j) ----
        const bool a00 = (sv0.x != 0.0f), a01 = (sv0.y != 0.0f);   // b0
        const bool a10 = (sv1.x != 0.0f), a11 = (sv1.y != 0.0f);   // b1
        const bool u0 = a00 | a10;
        const bool u1 = a01 | a11;
        const unsigned long long m0 = __ballot(u0);
        const unsigned long long m1 = __ballot(u1);
        if (lane == 0) {
            wc1[w] = __popcll(m0) + __popcll(m1);
            if (w == 2)   // k = 256 + 2*l + j ; k < 320 <=> l < 32
                wc1p = __popcll(m0 & 0xFFFFFFFFull) + __popcll(m1 & 0xFFFFFFFFull);
        }
        const int pre1 = __popcll(m0 & below) + __popcll(m1 & below);
        __syncthreads();                        // wc1 ready; prev stage-3 done

        // ---- stage 1b: deterministic ascending compaction (lex (lane,j) = asc k) ----
        {
            int base = 0;
            for (int i = 0; i < w; ++i) base += wc1[i];
            int p = base + pre1;
            if (u0) list1[p++] = (2 * tid)     | (a00 ? 0x10000 : 0) | (a10 ? 0x20000 : 0);
            if (u1) list1[p]   = (2 * tid + 1) | (a01 ? 0x10000 : 0) | (a11 ? 0x20000 : 0);
        }
        __syncthreads();                        // list1 ready

        // prefetch spikes for t+1; overlaps gather compute
        if (t + 1 < T_STEPS) {
            sv0 = *reinterpret_cast<const float2*>(sp0 + (size_t)(t + 1) * (BATCH * NLAB));
            sv1 = *reinterpret_cast<const float2*>(sp1 + (size_t)(t + 1) * (BATCH * NLAB));
        }

        // ---- stage 2: layer 1, cols h = 4*tid+c. kc split at k=320 ----
        bool sp00, sp01, sp02, sp03, sp10, sp11, sp12, sp13;
        int  preh;
        {
            const int nA = wc1[0] + wc1[1] + wc1p;
            const int n1 = wc1[0] + wc1[1] + wc1[2] + wc1[3];
            f32x2 xA[4], xB[4];
            gatherU(list1, 0,  nA, w1b, xA);
            gatherU(list1, nA, n1, w1b, xB);
#pragma unroll
            for (int j = 0; j < 4; ++j) {
                const f32x2 x1 = xA[j] + xB[j];            // v_pk_add, per-comp RN
                v1[j] = (v1[j] * 0.95f) + x1;              // pk_mul then pk_add (exact order)
            }
            sp00 = (v1[0].x > 1.0f); if (sp00) { c1[0]++; v1[0].x = 0.0f; }
            sp01 = (v1[0].y > 1.0f); if (sp01) { c1[1]++; v1[0].y = 0.0f; }
            sp02 = (v1[1].x > 1.0f); if (sp02) { c1[2]++; v1[1].x = 0.0f; }
            sp03 = (v1[1].y > 1.0f); if (sp03) { c1[3]++; v1[1].y = 0.0f; }
            sp10 = (v1[2].x > 1.0f); if (sp10) { c1[4]++; v1[2].x = 0.0f; }
            sp11 = (v1[2].y > 1.0f); if (sp11) { c1[5]++; v1[2].y = 0.0f; }
            sp12 = (v1[3].x > 1.0f); if (sp12) { c1[6]++; v1[3].x = 0.0f; }
            sp13 = (v1[3].y > 1.0f); if (sp13) { c1[7]++; v1[3].y = 0.0f; }

            // union per hidden h = 4*tid + c
            const bool uc0 = sp00 | sp10;
            const bool uc1 = sp01 | sp11;
            const bool uc2 = sp02 | sp12;
            const bool uc3 = sp03 | sp13;
            const unsigned long long b0m = __ballot(uc0);
            const unsigned long long b1m = __ballot(uc1);
            const unsigned long long b2m = __ballot(uc2);
            const unsigned long long b3m = __ballot(uc3);
            if (lane == 0) {
                wc2[w] = __popcll(b0m) + __popcll(b1m) + __popcll(b2m) + __popcll(b3m);
                // h = 256*w + 4*l + c ; boundaries 320/640/960 -> l<16 / l<32 / l<48
                if (w == 1)
                    wc2p[0] = __popcll(b0m & 0xFFFFull) + __popcll(b1m & 0xFFFFull)
                            + __popcll(b2m & 0xFFFFull) + __popcll(b3m & 0xFFFFull);
                if (w == 2)
                    wc2p[1] = __popcll(b0m & 0xFFFFFFFFull) + __popcll(b1m & 0xFFFFFFFFull)
                            + __popcll(b2m & 0xFFFFFFFFull) + __popcll(b3m & 0xFFFFFFFFull);
                if (w == 3)
                    wc2p[2] = __popcll(b0m & 0xFFFFFFFFFFFFull) + __popcll(b1m & 0xFFFFFFFFFFFFull)
                            + __popcll(b2m & 0xFFFFFFFFFFFFull) + __popcll(b3m & 0xFFFFFFFFFFFFull);
            }
            preh = __popcll(b0m & below) + __popcll(b1m & below)
                 + __popcll(b2m & below) + __popcll(b3m & below);
        }
        __syncthreads();                        // wc2 ready

        {
            int base = 0;
            for (int i = 0; i < w; ++i) base += wc2[i];
            int p = base + preh;                // own entries consecutive, c asc = h asc
            if (sp00 | sp10) list2[p++] = (4 * tid)     | (sp00 ? 0x10000 : 0) | (sp10 ? 0x20000 : 0);
            if (sp01 | sp11) list2[p++] = (4 * tid + 1) | (sp01 ? 0x10000 : 0) | (sp11 ? 0x20000 : 0);
            if (sp02 | sp12) list2[p++] = (4 * tid + 2) | (sp02 ? 0x10000 : 0) | (sp12 ? 0x20000 : 0);
            if (sp03 | sp13) list2[p]   = (4 * tid + 3) | (sp03 ? 0x10000 : 0) | (sp13 ? 0x20000 : 0);
        }
        __syncthreads();                        // list2 ready

        // ---- stage 3: layer 2. kc blocks at h = 320 / 640 / 960 ----
        {
            const int nA = wc2[0] + wc2p[0];
            const int nB = wc2[0] + wc2[1] + wc2p[1];
            const int nC = wc2[0] + wc2[1] + wc2[2] + wc2p[2];
            const int n2 = wc2[0] + wc2[1] + wc2[2] + wc2[3];
            f32x2 t1[4], t2[4], t3[4], t4[4];
            gatherU(list2, 0,  nA, w2b, t1);
            gatherU(list2, nA, nB, w2b, t2);
            gatherU(list2, nB, nC, w2b, t3);
            gatherU(list2, nC, n2, w2b, t4);
#pragma unroll
            for (int j = 0; j < 4; ++j) {
                const f32x2 x2 = ((t1[j] + t2[j]) + t3[j]) + t4[j];
                v2[j] = (v2[j] * 0.95f) + x2;
            }
            if (v2[0].x > 1.0f) { c2[0]++; v2[0].x = 0.0f; }
            if (v2[0].y > 1.0f) { c2[1]++; v2[0].y = 0.0f; }
            if (v2[1].x > 1.0f) { c2[2]++; v2[1].x = 0.0f; }
            if (v2[1].y > 1.0f) { c2[3]++; v2[1].y = 0.0f; }
            if (v2[2].x > 1.0f) { c2[4]++; v2[2].x = 0.0f; }
            if (v2[2].y > 1.0f) { c2[5]++; v2[2].y = 0.0f; }
            if (v2[3].x > 1.0f) { c2[6]++; v2[3].x = 0.0f; }
            if (v2[3].y > 1.0f) { c2[7]++; v2[3].y = 0.0f; }
        }
        __syncthreads();                        // lists/counts free for next iter
    }

    const float sc = 1.0f / 128.0f;
    {
        const float4 o = make_float4((float)c1[0] * sc, (float)c1[1] * sc,
                                     (float)c1[2] * sc, (float)c1[3] * sc);
        *reinterpret_cast<float4*>(out + (size_t)b0 * HID + 4 * tid) = o;
        const float4 o2 = make_float4((float)c1[4] * sc, (float)c1[5] * sc,
                                      (float)c1[6] * sc, (float)c1[7] * sc);
        *reinterpret_cast<float4*>(out + (size_t)(b0 + 1) * HID + 4 * tid) = o2;
    }
    {
        float* ob = out + (size_t)BATCH * HID;
        const float4 o = make_float4((float)c2[0] * sc, (float)c2[1] * sc,
                                     (float)c2[2] * sc, (float)c2[3] * sc);
        *reinterpret_cast<float4*>(ob + (size_t)b0 * SEM + 4 * tid) = o;
        const float4 o2 = make_float4((float)c2[4] * sc, (float)c2[5] * sc,
                                      (float)c2[6] * sc, (float)c2[7] * sc);
        *reinterpret_cast<float4*>(ob + (size_t)(b0 + 1) * SEM + 4 * tid) = o2;
    }
}

extern "C" void kernel_launch(void* const* d_in, const int* in_sizes, int n_in,
                              void* d_out, int out_size, void* d_ws, size_t ws_size,
                              hipStream_t stream) {
    const float* spikes = (const float*)d_in[0];  // (128, 512, 512)
    const float* W1     = (const float*)d_in[1];  // (1024, 512)
    const float* W2     = (const float*)d_in[2];  // (1024, 1024)
    float* out = (float*)d_out;

    float* w1t = (float*)d_ws;                    // (512, 1024)
    float* w2t = w1t + (size_t)NLAB * HID;        // (1024, 1024) — 6 MB total

    dim3 tb(32, 8);
    transpose32<<<dim3(NLAB / 32, HID / 32), tb, 0, stream>>>(W1, w1t, HID, NLAB);
    transpose32<<<dim3(HID / 32, SEM / 32),  tb, 0, stream>>>(W2, w2t, SEM, HID);

    snn_kernel<<<BATCH / 2, 256, 0, stream>>>(spikes, w1t, w2t, out);
}

// Round 6
// 1561.716 us; speedup vs baseline: 1.3871x; 1.2077x over previous
//
#include <hip/hip_runtime.h>

// LIF two-layer SNN, bit-exact emulation of the f32 OpenBLAS-style reference
// (kc=320 K-blocking, sequential ascending-k f32 chains per block, block
// partials combined in order; LIF = separate f32 mul then add).
// Round 10: re-submit of round-9 (identical to the verified round-6 kernel);
// round-9's bench failed on container acquisition, not on the kernel.
// Best verified: 1564 us harness, 1483 us steady-state = 34.8 TB/s L2-side
// gather bandwidth ~= 100% of the measured 34.5 TB/s L2 aggregate ceiling.
// Both byte-reduction attempts (r7: dwordx2 union, +45%; r8: 256-block
// union, +23%) regressed by leaving the 8-waves/CU + dwordx4 + 512-block
// operating point. This IS that point.

#define T_STEPS 128
#define BATCH   512
#define NLAB    512
#define HID     1024
#define SEM     1024

// 32x32 tiled transpose, block = (32,8). R,C multiples of 32. Exact copies.
__global__ __launch_bounds__(256) void transpose32(const float* __restrict__ in,
                                                   float* __restrict__ out,
                                                   int R, int C) {
    __shared__ float tile[32][33];
    const int c0 = blockIdx.x * 32, r0 = blockIdx.y * 32;
    const int x = threadIdx.x, y0 = threadIdx.y;
#pragma unroll
    for (int i = 0; i < 32; i += 8)
        tile[y0 + i][x] = in[(size_t)(r0 + y0 + i) * C + (c0 + x)];
    __syncthreads();
#pragma unroll
    for (int i = 0; i < 32; i += 8)
        out[(size_t)(c0 + y0 + i) * R + (r0 + x)] = tile[x][y0 + i];
}

// Sequential ascending-k f32 add chains over list[lo..hi) of weight rows
// (row stride 1024 floats), 4 independent columns per thread via dwordx4,
// 16-deep load pipeline, wave-uniform scalar addressing. Per-column fadd
// order is strictly k-ascending -> bit-exact.
__device__ __forceinline__ void gather4(const int* __restrict__ list,
                                        int lo, int hi,
                                        const float* __restrict__ base, // w + 4*tid
                                        float s[4]) {
    float s0 = 0.0f, s1 = 0.0f, s2 = 0.0f, s3 = 0.0f;
    int k = lo;
    for (; k + 16 <= hi; k += 16) {
        float4 wv[16];
#pragma unroll
        for (int j = 0; j < 16; ++j) {
            const int row = __builtin_amdgcn_readfirstlane(list[k + j]);
            wv[j] = *reinterpret_cast<const float4*>(base + ((size_t)row << 10));
        }
#pragma unroll
        for (int j = 0; j < 16; ++j) {
            s0 = __fadd_rn(s0, wv[j].x);
            s1 = __fadd_rn(s1, wv[j].y);
            s2 = __fadd_rn(s2, wv[j].z);
            s3 = __fadd_rn(s3, wv[j].w);
        }
    }
    for (; k + 8 <= hi; k += 8) {
        float4 wv[8];
#pragma unroll
        for (int j = 0; j < 8; ++j) {
            const int row = __builtin_amdgcn_readfirstlane(list[k + j]);
            wv[j] = *reinterpret_cast<const float4*>(base + ((size_t)row << 10));
        }
#pragma unroll
        for (int j = 0; j < 8; ++j) {
            s0 = __fadd_rn(s0, wv[j].x);
            s1 = __fadd_rn(s1, wv[j].y);
            s2 = __fadd_rn(s2, wv[j].z);
            s3 = __fadd_rn(s3, wv[j].w);
        }
    }
    for (; k < hi; ++k) {
        const int row = __builtin_amdgcn_readfirstlane(list[k]);
        const float4 wv = *reinterpret_cast<const float4*>(base + ((size_t)row << 10));
        s0 = __fadd_rn(s0, wv.x);
        s1 = __fadd_rn(s1, wv.y);
        s2 = __fadd_rn(s2, wv.z);
        s3 = __fadd_rn(s3, wv.w);
    }
    s[0] = s0; s[1] = s1; s[2] = s2; s[3] = s3;
}

__global__ __launch_bounds__(256)
void snn_kernel(const float* __restrict__ spikes,   // (T, B, NLAB)
                const float* __restrict__ w1t,      // (NLAB, HID) = W1^T
                const float* __restrict__ w2t,      // (HID, SEM)  = W2^T
                float* __restrict__ out) {          // (B*HID) ++ (B*SEM)
    __shared__ int wc1[4];            // per-wave active counts, input spikes
    __shared__ int wc1p;              // partial: active k in [256,320) (wave 2, l<32)
    __shared__ int wc2[4];            // per-wave spike counts, layer 1
    __shared__ int wc2p[3];           // partials at h=320 (w1,l<16), 640 (w2,l<32), 960 (w3,l<48)
    __shared__ __align__(16) int list1[NLAB];   // ascending active inputs
    __shared__ __align__(16) int list2[HID];    // ascending spiking hidden

    const int b    = blockIdx.x;
    const int tid  = threadIdx.x;               // 0..255
    const int w    = tid >> 6;                  // wave 0..3
    const int lane = tid & 63;
    const unsigned long long below = (1ull << lane) - 1ull;

    float v1[4] = {0.0f, 0.0f, 0.0f, 0.0f};
    float v2[4] = {0.0f, 0.0f, 0.0f, 0.0f};
    int   c1[4] = {0, 0, 0, 0};
    int   c2[4] = {0, 0, 0, 0};

    // thread covers inputs k = 2*tid, 2*tid+1 and output columns 4*tid..4*tid+3
    const float* sp_b = spikes + (size_t)b * NLAB + 2 * tid;
    const float* w1b  = w1t + 4 * tid;
    const float* w2b  = w2t + 4 * tid;

    // prefetch spikes for t=0
    float2 sv = *reinterpret_cast<const float2*>(sp_b);

    for (int t = 0; t < T_STEPS; ++t) {
        // ---- stage 1a: ballots + per-wave counts of active inputs ----
        const bool a0 = (sv.x != 0.0f);
        const bool a1 = (sv.y != 0.0f);
        const unsigned long long m0 = __ballot(a0);
        const unsigned long long m1 = __ballot(a1);
        if (lane == 0) {
            wc1[w] = __popcll(m0) + __popcll(m1);
            if (w == 2)   // k = 256 + 2*l + j ; k < 320 <=> l < 32
                wc1p = __popcll(m0 & 0xFFFFFFFFull) + __popcll(m1 & 0xFFFFFFFFull);
        }
        const int pre1 = __popcll(m0 & below) + __popcll(m1 & below);
        __syncthreads();                        // wc1 ready; prev stage-3 done

        // ---- stage 1b: deterministic ascending compaction (lex (lane,j) = asc k) ----
        {
            int base = 0;
            for (int i = 0; i < w; ++i) base += wc1[i];
            int p = base + pre1;
            if (a0) list1[p++] = 2 * tid;
            if (a1) list1[p]   = 2 * tid + 1;
        }
        __syncthreads();                        // list1 ready

        // prefetch spikes for t+1; overlaps stage-2/3 gather compute
        if (t + 1 < T_STEPS)
            sv = *reinterpret_cast<const float2*>(sp_b + (size_t)(t + 1) * (BATCH * NLAB));

        // ---- stage 2: layer 1, h = 4*tid+j. kc blocks [0,320),[320,512) ----
        bool spk0, spk1, spk2, spk3;
        int  preh;
        {
            const int nA = wc1[0] + wc1[1] + wc1p;
            const int n1 = wc1[0] + wc1[1] + wc1[2] + wc1[3];
            float xA[4], xB[4];
            gather4(list1, 0,  nA, w1b, xA);
            gather4(list1, nA, n1, w1b, xB);
#pragma unroll
            for (int j = 0; j < 4; ++j) {
                const float x1 = __fadd_rn(xA[j], xB[j]);
                v1[j] = __fadd_rn(__fmul_rn(0.95f, v1[j]), x1);
            }
            spk0 = (v1[0] > 1.0f); if (spk0) { c1[0]++; v1[0] = 0.0f; }
            spk1 = (v1[1] > 1.0f); if (spk1) { c1[1]++; v1[1] = 0.0f; }
            spk2 = (v1[2] > 1.0f); if (spk2) { c1[2]++; v1[2] = 0.0f; }
            spk3 = (v1[3] > 1.0f); if (spk3) { c1[3]++; v1[3] = 0.0f; }

            const unsigned long long b0 = __ballot(spk0);
            const unsigned long long b1 = __ballot(spk1);
            const unsigned long long b2 = __ballot(spk2);
            const unsigned long long b3 = __ballot(spk3);
            if (lane == 0) {
                wc2[w] = __popcll(b0) + __popcll(b1) + __popcll(b2) + __popcll(b3);
                // h = 256*w + 4*l + j ; boundaries 320/640/960 -> l<16 / l<32 / l<48
                if (w == 1)
                    wc2p[0] = __popcll(b0 & 0xFFFFull) + __popcll(b1 & 0xFFFFull)
                            + __popcll(b2 & 0xFFFFull) + __popcll(b3 & 0xFFFFull);
                if (w == 2)
                    wc2p[1] = __popcll(b0 & 0xFFFFFFFFull) + __popcll(b1 & 0xFFFFFFFFull)
                            + __popcll(b2 & 0xFFFFFFFFull) + __popcll(b3 & 0xFFFFFFFFull);
                if (w == 3)
                    wc2p[2] = __popcll(b0 & 0xFFFFFFFFFFFFull) + __popcll(b1 & 0xFFFFFFFFFFFFull)
                            + __popcll(b2 & 0xFFFFFFFFFFFFull) + __popcll(b3 & 0xFFFFFFFFFFFFull);
            }
            preh = __popcll(b0 & below) + __popcll(b1 & below)
                 + __popcll(b2 & below) + __popcll(b3 & below);
        }
        __syncthreads();                        // wc2 ready

        {
            int base = 0;
            for (int i = 0; i < w; ++i) base += wc2[i];
            int p = base + preh;                // own-lane entries consecutive, j asc
            if (spk0) list2[p++] = 4 * tid;
            if (spk1) list2[p++] = 4 * tid + 1;
            if (spk2) list2[p++] = 4 * tid + 2;
            if (spk3) list2[p]   = 4 * tid + 3;
        }
        __syncthreads();                        // list2 ready

        // ---- stage 3: layer 2, s = 4*tid+j. kc blocks 320/320/320/64 ----
        {
            const int nA = wc2[0] + wc2p[0];
            const int nB = wc2[0] + wc2[1] + wc2p[1];
            const int nC = wc2[0] + wc2[1] + wc2[2] + wc2p[2];
            const int n2 = wc2[0] + wc2[1] + wc2[2] + wc2[3];
            float t1[4], t2[4], t3[4], t4[4];
            gather4(list2, 0,  nA, w2b, t1);
            gather4(list2, nA, nB, w2b, t2);
            gather4(list2, nB, nC, w2b, t3);
            gather4(list2, nC, n2, w2b, t4);
#pragma unroll
            for (int j = 0; j < 4; ++j) {
                const float x2 = __fadd_rn(__fadd_rn(__fadd_rn(t1[j], t2[j]), t3[j]), t4[j]);
                v2[j] = __fadd_rn(__fmul_rn(0.95f, v2[j]), x2);
                if (v2[j] > 1.0f) { c2[j]++; v2[j] = 0.0f; }
            }
        }
        __syncthreads();                        // list2/wc2 free for next iter
    }

    const float sc = 1.0f / 128.0f;
    const float4 o1 = make_float4((float)c1[0] * sc, (float)c1[1] * sc,
                                  (float)c1[2] * sc, (float)c1[3] * sc);
    *reinterpret_cast<float4*>(out + (size_t)b * HID + 4 * tid) = o1;
    const float4 o2 = make_float4((float)c2[0] * sc, (float)c2[1] * sc,
                                  (float)c2[2] * sc, (float)c2[3] * sc);
    *reinterpret_cast<float4*>(out + (size_t)BATCH * HID + (size_t)b * SEM + 4 * tid) = o2;
}

extern "C" void kernel_launch(void* const* d_in, const int* in_sizes, int n_in,
                              void* d_out, int out_size, void* d_ws, size_t ws_size,
                              hipStream_t stream) {
    const float* spikes = (const float*)d_in[0];  // (128, 512, 512)
    const float* W1     = (const float*)d_in[1];  // (1024, 512)
    const float* W2     = (const float*)d_in[2];  // (1024, 1024)
    float* out = (float*)d_out;

    float* w1t = (float*)d_ws;                    // (512, 1024)
    float* w2t = w1t + (size_t)NLAB * HID;        // (1024, 1024) — 6 MB total

    dim3 tb(32, 8);
    transpose32<<<dim3(NLAB / 32, HID / 32), tb, 0, stream>>>(W1, w1t, HID, NLAB);
    transpose32<<<dim3(HID / 32, SEM / 32),  tb, 0, stream>>>(W2, w2t, SEM, HID);

    snn_kernel<<<BATCH, 256, 0, stream>>>(spikes, w1t, w2t, out);
}